// Round 14
// baseline (2247.828 us; speedup 1.0000x reference)
//
#include <hip/hip_runtime.h>
#include <hip/hip_bf16.h>
#include <stdint.h>

#define NN 100000
#define EE 400000
#define ND 4096
#define DD 512
#define FF 8000
#define EMB 300
#define HID 600
#define NL 5
#define TCH 50176     // M-chunk rows, 2 chunks
#define MPAD 100096

typedef unsigned short u16;
typedef _Float16 f16x8 __attribute__((ext_vector_type(8)));
typedef float f32x4 __attribute__((ext_vector_type(4)));
typedef float f32x2 __attribute__((ext_vector_type(2)));

static __device__ inline u16 f2h(float v) {
    union { _Float16 h; u16 u; } c; c.h = (_Float16)v; return c.u;
}
static __device__ inline float h2f(u16 u) {
    union { u16 u; _Float16 h; } c; c.u = u; return (float)c.h;
}
static __device__ inline uint32_t pk2(float a, float b) {
    return (uint32_t)f2h(a) | ((uint32_t)f2h(b) << 16);
}
static __device__ inline f32x2 up2(uint32_t w) {
    f32x2 r; r.x = h2f((u16)(w & 0xffff)); r.y = h2f((u16)(w >> 16)); return r;
}
// LDS XOR swizzle: 16B block cb of row -> cb ^ ((row>>1)&3); frag reads 2-way (free)
static __device__ inline int loff(int row, int cb) {
    return row * 32 + ((cb ^ (((row) >> 1) & 3)) * 8);
}

// ---------------- node feature init (fp16, pad cols zeroed) ----------------
static __global__ void k_init_h(const int* __restrict__ x, const float* __restrict__ ae1,
                                const float* __restrict__ ae2, uint32_t* __restrict__ h) {
    int idx = blockIdx.x * 256 + threadIdx.x;
    if (idx >= NN * 160) return;
    int n = idx / 160, cw = idx - n * 160;
    int c = 2 * cw;
    int x0 = x[2 * n], x1 = x[2 * n + 1];
    float v0 = 0.f, v1 = 0.f;
    if (c < EMB)     v0 = ae1[x0 * EMB + c] + ae2[x1 * EMB + c];
    if (c + 1 < EMB) v1 = ae1[x0 * EMB + c + 1] + ae2[x1 * EMB + c + 1];
    h[idx] = pk2(v0, v1);
}

// ---------------- degree + edge-attr histograms ----------------
static __global__ void k_count(const int* __restrict__ ei, const int* __restrict__ ea,
                               int* __restrict__ deg, int* __restrict__ cnt1, int* __restrict__ cnt2) {
    int e = blockIdx.x * 256 + threadIdx.x;
    if (e >= EE) return;
    int dst = ei[EE + e];
    atomicAdd(&deg[dst], 1);
    atomicAdd(&cnt1[dst * 3 + ea[2 * e]], 1);
    atomicAdd(&cnt2[dst * 3 + ea[2 * e + 1]], 1);
}

// ---------------- generic 3-pass exclusive scan ----------------
static __global__ void k_scan1(const int* __restrict__ in, int* __restrict__ incl,
                               int* __restrict__ bsum, int L) {
    __shared__ int s[256];
    int t = threadIdx.x, i = blockIdx.x * 256 + t;
    int v = (i < L) ? in[i] : 0;
    s[t] = v; __syncthreads();
    for (int o = 1; o < 256; o <<= 1) {
        int xv = (t >= o) ? s[t - o] : 0; __syncthreads();
        s[t] += xv; __syncthreads();
    }
    if (i < L) incl[i] = s[t];
    if (t == 255) bsum[blockIdx.x] = s[255];
}

static __global__ void k_scan2(const int* __restrict__ bsum, int* __restrict__ boff, int nb) {
    __shared__ int s[1024];
    int t = threadIdx.x;
    int v = (t < nb) ? bsum[t] : 0;
    s[t] = v; __syncthreads();
    for (int o = 1; o < 1024; o <<= 1) {
        int xv = (t >= o) ? s[t - o] : 0; __syncthreads();
        s[t] += xv; __syncthreads();
    }
    if (t < nb) boff[t] = s[t] - v;
}

static __global__ void k_scan3(const int* __restrict__ in, const int* __restrict__ incl,
                               const int* __restrict__ boff, int* __restrict__ op,
                               int* __restrict__ cursor, int L) {
    int i = blockIdx.x * 256 + threadIdx.x;
    if (i >= L) return;
    int ex = incl[i] - in[i] + boff[i / 256];
    op[i] = ex;
    if (cursor) cursor[i] = ex;
    if (i == L - 1) op[L] = ex + in[i];
}

// ---------------- CSR scatter ----------------
static __global__ void k_scatter(const int* __restrict__ ei, int* __restrict__ cursor,
                                 int* __restrict__ col) {
    int e = blockIdx.x * 256 + threadIdx.x;
    if (e >= EE) return;
    int dst = ei[EE + e], src = ei[e];
    int p = atomicAdd(&cursor[dst], 1);
    col[p] = src;
}

// ---------------- GIN aggregation: grid-stride, 4-way unrolled gathers --------
static __global__ void k_aggr(const u16* __restrict__ h, u16* __restrict__ ag,
                              const int* __restrict__ rowptr, const int* __restrict__ col,
                              const int* __restrict__ cnt1, const int* __restrict__ cnt2,
                              const float* __restrict__ ge1l, const float* __restrict__ ge2l,
                              const float* __restrict__ scv, int relu) {
    __shared__ float se[7 * 320];
    for (int idx = threadIdx.x; idx < 7 * 320; idx += 256) {
        int g = idx / 320, c = idx - g * 320;
        float v = 0.f;
        if (c < EMB) {
            if (g < 3) v = ge1l[g * EMB + c];
            else if (g < 6) v = ge2l[(g - 3) * EMB + c];
            else v = ge1l[4 * EMB + c] + ge2l[c];
        }
        se[idx] = v;
    }
    __syncthreads();
    int wv = threadIdx.x >> 6, lane = threadIdx.x & 63;

    int cw[3];
    f32x2 sc2[3], sh2[3];
#pragma unroll
    for (int j = 0; j < 3; j++) {
        cw[j] = lane + 64 * j;
        if (cw[j] < 160) {
            int c = 2 * cw[j];
            if (scv) {
                sc2[j] = *(const f32x2*)&scv[c];
                sh2[j] = *(const f32x2*)&scv[320 + c];
            } else { sc2[j] = (f32x2){1.f, 1.f}; sh2[j] = (f32x2){0.f, 0.f}; }
        }
    }

    for (int g0 = blockIdx.x * 4; g0 < NN; g0 += gridDim.x * 4) {
        int n = g0 + wv;
        if (n >= NN) continue;
        float c1a = (float)cnt1[n * 3], c1b = (float)cnt1[n * 3 + 1], c1c = (float)cnt1[n * 3 + 2];
        float c2a = (float)cnt2[n * 3], c2b = (float)cnt2[n * 3 + 1], c2c = (float)cnt2[n * 3 + 2];

        f32x2 acc[3];
        const uint32_t* hn = (const uint32_t*)(h + (size_t)n * 320);
#pragma unroll
        for (int j = 0; j < 3; j++) {
            if (cw[j] < 160) {
                int c = 2 * cw[j];
                f32x2 v = up2(hn[cw[j]]) * sc2[j] + sh2[j];
                if (relu) { v.x = fmaxf(v.x, 0.f); v.y = fmaxf(v.y, 0.f); }
                acc[j] = v + *(const f32x2*)&se[6 * 320 + c]
                       + c1a * *(const f32x2*)&se[c]
                       + c1b * *(const f32x2*)&se[320 + c]
                       + c1c * *(const f32x2*)&se[640 + c]
                       + c2a * *(const f32x2*)&se[960 + c]
                       + c2b * *(const f32x2*)&se[1280 + c]
                       + c2c * *(const f32x2*)&se[1600 + c];
            }
        }
        int p = rowptr[n], end = rowptr[n + 1];
        for (; p + 4 <= end; p += 4) {
            const uint32_t* h0 = (const uint32_t*)(h + (size_t)col[p] * 320);
            const uint32_t* h1 = (const uint32_t*)(h + (size_t)col[p + 1] * 320);
            const uint32_t* h2 = (const uint32_t*)(h + (size_t)col[p + 2] * 320);
            const uint32_t* h3 = (const uint32_t*)(h + (size_t)col[p + 3] * 320);
            uint32_t w0[3], w1[3], w2[3], w3[3];
#pragma unroll
            for (int j = 0; j < 3; j++) {
                if (cw[j] < 160) {
                    w0[j] = h0[cw[j]]; w1[j] = h1[cw[j]];
                    w2[j] = h2[cw[j]]; w3[j] = h3[cw[j]];
                }
            }
#pragma unroll
            for (int j = 0; j < 3; j++) {
                if (cw[j] < 160) {
                    f32x2 v0 = up2(w0[j]) * sc2[j] + sh2[j];
                    if (relu) { v0.x = fmaxf(v0.x, 0.f); v0.y = fmaxf(v0.y, 0.f); }
                    acc[j] += v0;
                    f32x2 v1 = up2(w1[j]) * sc2[j] + sh2[j];
                    if (relu) { v1.x = fmaxf(v1.x, 0.f); v1.y = fmaxf(v1.y, 0.f); }
                    acc[j] += v1;
                    f32x2 v2 = up2(w2[j]) * sc2[j] + sh2[j];
                    if (relu) { v2.x = fmaxf(v2.x, 0.f); v2.y = fmaxf(v2.y, 0.f); }
                    acc[j] += v2;
                    f32x2 v3 = up2(w3[j]) * sc2[j] + sh2[j];
                    if (relu) { v3.x = fmaxf(v3.x, 0.f); v3.y = fmaxf(v3.y, 0.f); }
                    acc[j] += v3;
                }
            }
        }
        for (; p + 2 <= end; p += 2) {
            const uint32_t* h0 = (const uint32_t*)(h + (size_t)col[p] * 320);
            const uint32_t* h1 = (const uint32_t*)(h + (size_t)col[p + 1] * 320);
            uint32_t w0[3], w1[3];
#pragma unroll
            for (int j = 0; j < 3; j++)
                if (cw[j] < 160) { w0[j] = h0[cw[j]]; w1[j] = h1[cw[j]]; }
#pragma unroll
            for (int j = 0; j < 3; j++) {
                if (cw[j] < 160) {
                    f32x2 v0 = up2(w0[j]) * sc2[j] + sh2[j];
                    if (relu) { v0.x = fmaxf(v0.x, 0.f); v0.y = fmaxf(v0.y, 0.f); }
                    acc[j] += v0;
                    f32x2 v1 = up2(w1[j]) * sc2[j] + sh2[j];
                    if (relu) { v1.x = fmaxf(v1.x, 0.f); v1.y = fmaxf(v1.y, 0.f); }
                    acc[j] += v1;
                }
            }
        }
        for (; p < end; ++p) {
            const uint32_t* hr = (const uint32_t*)(h + (size_t)col[p] * 320);
#pragma unroll
            for (int j = 0; j < 3; j++) {
                if (cw[j] < 160) {
                    f32x2 v = up2(hr[cw[j]]) * sc2[j] + sh2[j];
                    if (relu) { v.x = fmaxf(v.x, 0.f); v.y = fmaxf(v.y, 0.f); }
                    acc[j] += v;
                }
            }
        }
        uint32_t* ao = (uint32_t*)(ag + (size_t)n * 320);
#pragma unroll
        for (int j = 0; j < 3; j++)
            if (cw[j] < 160) ao[cw[j]] = pk2(acc[j].x, acc[j].y);
    }
}

// ---------------- weight packing: transposed, padded, fp16 ------------
static __global__ void k_packW1(const float* __restrict__ W1, u16* __restrict__ W1p) {
    int idx = blockIdx.x * 256 + threadIdx.x;
    const int per = 640 * 320;
    if (idx >= NL * per) return;
    int l = idx / per, rem = idx % per;
    int n = rem / 320, k = rem % 320;
    float v = (k < EMB && n < HID) ? W1[(size_t)l * EMB * HID + (size_t)k * HID + n] : 0.f;
    W1p[idx] = f2h(v);
}

static __global__ void k_packW2(const float* __restrict__ W2, u16* __restrict__ W2p) {
    int idx = blockIdx.x * 256 + threadIdx.x;
    const int per = 384 * 640;
    if (idx >= NL * per) return;
    int l = idx / per, rem = idx % per;
    int n = rem / 640, k = rem % 640;
    float v = (k < HID && n < EMB) ? W2[(size_t)l * HID * EMB + (size_t)k * EMB + n] : 0.f;
    W2p[idx] = f2h(v);
}

static __global__ void k_packb(const float* __restrict__ b1, const float* __restrict__ b2,
                               float* __restrict__ b1p, float* __restrict__ b2p) {
    int idx = blockIdx.x * 256 + threadIdx.x;
    if (idx < NL * 640) {
        int l = idx / 640, n = idx % 640;
        b1p[idx] = (n < HID) ? b1[l * HID + n] : 0.f;
    } else if (idx < NL * 640 + NL * 384) {
        int j = idx - NL * 640;
        int l = j / 384, n = j % 384;
        b2p[j] = (n < EMB) ? b2[l * EMB + n] : 0.f;
    }
}

// Mpt[p][m][k] = fp16(E1[a][k*600+m] + E2[b][k*600+m]), 640x640 zero-padded
static __global__ void k_precompMt(const float* __restrict__ E1, const float* __restrict__ E2,
                                   u16* __restrict__ Mpt) {
    __shared__ float sT[32][33];
    int p = blockIdx.x, mt = blockIdx.y, kt = blockIdx.z;
    int a = p / 3, b = p % 3;
    const float* e1 = E1 + (size_t)a * 360000;
    const float* e2 = E2 + (size_t)b * 360000;
    int tx = threadIdx.x & 31, ty = threadIdx.x >> 5;
#pragma unroll
    for (int it = 0; it < 4; it++) {
        int k = kt * 32 + ty + it * 8;
        int m = mt * 32 + tx;
        float v = 0.f;
        if (k < HID && m < HID) v = e1[k * HID + m] + e2[k * HID + m];
        sT[ty + it * 8][tx] = v;
    }
    __syncthreads();
#pragma unroll
    for (int it = 0; it < 4; it++) {
        int m = mt * 32 + ty + it * 8;
        int k = kt * 32 + tx;
        Mpt[(size_t)p * 640 * 640 + (size_t)m * 640 + k] = f2h(sT[tx][ty + it * 8]);
    }
}

// ---------------- GEMM1: t = relu(ag@W1p + b1). BM=128, BN=320, 512 thr -----
// 8 waves 2Mx4N, per-wave 64x80 (acc[4][5]). grid (2, mt): A read only 2x.
static __global__ __launch_bounds__(512) void k_mfma1(
        const u16* __restrict__ A, const u16* __restrict__ B,
        const float* __restrict__ bias, u16* __restrict__ Out) {
    __shared__ __align__(16) u16 sA[128 * 32];   //  8 KB
    __shared__ __align__(16) u16 sB[320 * 32];   // 20 KB
    int tid = threadIdx.x, lane = tid & 63, wv = tid >> 6;
    int wm = wv >> 2, wn = wv & 3;
    int m0 = blockIdx.y * 128, n0 = blockIdx.x * 320;
    int sr = tid >> 2, scb = tid & 3;

    uint4 rA, rB[3];
    auto do_load = [&](int ks) {
        int kk = ks * 32;
        rA = *(const uint4*)&A[(size_t)(m0 + sr) * 320 + kk + scb * 8];
#pragma unroll
        for (int j = 0; j < 3; j++) {
            int idx = tid + 512 * j;
            if (idx < 1280) {
                int row = idx >> 2, cb = idx & 3;
                rB[j] = *(const uint4*)&B[(size_t)(n0 + row) * 320 + kk + cb * 8];
            }
        }
    };
    do_load(0);

    f32x4 acc[4][5];
#pragma unroll
    for (int i = 0; i < 4; i++)
#pragma unroll
        for (int j = 0; j < 5; j++) { acc[i][j][0]=0.f; acc[i][j][1]=0.f; acc[i][j][2]=0.f; acc[i][j][3]=0.f; }

    int lrow = lane & 15, lcb = lane >> 4;
    for (int ks = 0; ks < 10; ++ks) {
        __syncthreads();
        *(uint4*)&sA[loff(sr, scb)] = rA;
#pragma unroll
        for (int j = 0; j < 3; j++) {
            int idx = tid + 512 * j;
            if (idx < 1280) {
                int row = idx >> 2, cb = idx & 3;
                *(uint4*)&sB[loff(row, cb)] = rB[j];
            }
        }
        __syncthreads();
        if (ks + 1 < 10) do_load(ks + 1);
        f16x8 af[4], bf[5];
#pragma unroll
        for (int mf = 0; mf < 4; mf++) af[mf] = *(const f16x8*)&sA[loff(wm * 64 + mf * 16 + lrow, lcb)];
#pragma unroll
        for (int nf = 0; nf < 5; nf++) bf[nf] = *(const f16x8*)&sB[loff(wn * 80 + nf * 16 + lrow, lcb)];
#pragma unroll
        for (int mf = 0; mf < 4; mf++)
#pragma unroll
            for (int nf = 0; nf < 5; nf++)
                acc[mf][nf] = __builtin_amdgcn_mfma_f32_16x16x32_f16(af[mf], bf[nf], acc[mf][nf], 0, 0, 0);
    }
    int lrow4 = (lane >> 4) * 4, lcol = lane & 15;
#pragma unroll
    for (int nf = 0; nf < 5; nf++) {
        int colg = n0 + wn * 80 + nf * 16 + lcol;
        float bv = bias[colg];
#pragma unroll
        for (int mf = 0; mf < 4; mf++)
#pragma unroll
            for (int rg = 0; rg < 4; rg++) {
                int row = m0 + wm * 64 + mf * 16 + lrow4 + rg;
                Out[(size_t)row * 640 + colg] = f2h(fmaxf(acc[mf][nf][rg] + bv, 0.f));
            }
    }
}

// ---------------- GEMM2 (round-11): h = t@W2p+b2 + fused BN stats -----------
// BM=64, BN=128, K=640. grid (3, M/64)
static __global__ __launch_bounds__(256) void k_mfma2(
        const u16* __restrict__ A, const u16* __restrict__ B,
        const float* __restrict__ bias, u16* __restrict__ Out, int Mc,
        float* __restrict__ colsum, float* __restrict__ colsq) {
    __shared__ __align__(16) u16 sA[64 * 32];
    __shared__ __align__(16) u16 sB[128 * 32];
    int tid = threadIdx.x;
    int lane = tid & 63, wv = tid >> 6;
    int wn = wv;
    int m0 = blockIdx.y * 64;
    int n0 = blockIdx.x * 128;
    int sr = tid >> 2, scb = tid & 3;

    uint4 rA0, rB0, rB1;
    auto do_load = [&](int ks) {
        int kk = ks * 32;
        rA0 = *(const uint4*)&A[(size_t)(m0 + sr) * 640 + kk + scb * 8];
        const u16* bs = B + (size_t)(n0 + sr) * 640 + kk + scb * 8;
        rB0 = *(const uint4*)bs;
        rB1 = *(const uint4*)(bs + (size_t)64 * 640);
    };
    do_load(0);

    f32x4 acc[4][2];
#pragma unroll
    for (int i = 0; i < 4; i++)
#pragma unroll
        for (int j = 0; j < 2; j++) { acc[i][j][0]=0.f; acc[i][j][1]=0.f; acc[i][j][2]=0.f; acc[i][j][3]=0.f; }

    int lrow = lane & 15, lcb = lane >> 4;
    for (int ks = 0; ks < 20; ++ks) {
        __syncthreads();
        *(uint4*)&sA[loff(sr, scb)] = rA0;
        *(uint4*)&sB[loff(sr, scb)] = rB0;
        *(uint4*)&sB[loff(sr + 64, scb)] = rB1;
        __syncthreads();
        if (ks + 1 < 20) do_load(ks + 1);
        f16x8 af[4], bfr[2];
#pragma unroll
        for (int mf = 0; mf < 4; ++mf) af[mf] = *(const f16x8*)&sA[loff(mf * 16 + lrow, lcb)];
#pragma unroll
        for (int nf = 0; nf < 2; ++nf) bfr[nf] = *(const f16x8*)&sB[loff(wn * 32 + nf * 16 + lrow, lcb)];
#pragma unroll
        for (int mf = 0; mf < 4; ++mf)
#pragma unroll
            for (int nf = 0; nf < 2; ++nf)
                acc[mf][nf] = __builtin_amdgcn_mfma_f32_16x16x32_f16(af[mf], bfr[nf], acc[mf][nf], 0, 0, 0);
    }

    int lrow4 = (lane >> 4) * 4, lcol = lane & 15;
#pragma unroll
    for (int nf = 0; nf < 2; ++nf) {
        int colg = n0 + wn * 32 + nf * 16 + lcol;
        float bv = bias[colg];
        float s = 0.f, q = 0.f;
#pragma unroll
        for (int mf = 0; mf < 4; ++mf)
#pragma unroll
            for (int rg = 0; rg < 4; ++rg) {
                int rowl = m0 + mf * 16 + lrow4 + rg;
                float v = acc[mf][nf][rg] + bv;
                if (rowl < Mc) {
                    s += v; q += v * v;
                    if (colg < EMB) Out[(size_t)rowl * 320 + colg] = f2h(v);
                }
            }
        s += __shfl_xor(s, 16); s += __shfl_xor(s, 32);
        q += __shfl_xor(q, 16); q += __shfl_xor(q, 32);
        if (lane < 16) { atomicAdd(&colsum[colg], s); atomicAdd(&colsq[colg], q); }
    }
}

// ---------------- BN scale/shift (pad cols -> 0) ----------------
static __global__ void k_bnfinal(const float* __restrict__ colsum, const float* __restrict__ colsq,
                                 const float* __restrict__ g, const float* __restrict__ b,
                                 float* __restrict__ scv) {
    int c = threadIdx.x;
    if (c >= 320) return;
    if (c >= EMB) { scv[c] = 0.f; scv[320 + c] = 0.f; return; }
    float mean = colsum[c] * (1.f / NN);
    float var = colsq[c] * (1.f / NN) - mean * mean;
    float rs = rsqrtf(var + 1e-5f);
    float sc = rs * g[c];
    scv[c] = sc;
    scv[320 + c] = b[c] - mean * sc;
}

// ---------------- fragment pooling (applies final BN after mean) ----------------
static __global__ void k_fragcnt(const int* __restrict__ fb, int* __restrict__ fcnt) {
    int i = blockIdx.x * 256 + threadIdx.x;
    if (i >= NN) return;
    atomicAdd(&fcnt[fb[i]], 1);
}

static __global__ void k_fragmean(const u16* __restrict__ h, const int* __restrict__ fstart,
                                  const float* __restrict__ scv, float* __restrict__ fm) {
    int wv = threadIdx.x >> 6, lane = threadIdx.x & 63;
    int f = blockIdx.x * 4 + wv;
    if (f >= FF) return;
    int beg = fstart[f], end = fstart[f + 1];
    float inv = (end > beg) ? 1.f / (float)(end - beg) : 0.f;
    float a0[3], a1[3]; int cw[3];
#pragma unroll
    for (int j = 0; j < 3; j++) { cw[j] = lane + 64 * j; a0[j] = 0.f; a1[j] = 0.f; }
    for (int r = beg; r < end; ++r) {
        const uint32_t* hr = (const uint32_t*)(h + (size_t)r * 320);
#pragma unroll
        for (int j = 0; j < 3; j++)
            if (cw[j] < 160) {
                uint32_t hv = hr[cw[j]];
                a0[j] += h2f((u16)(hv & 0xffff)); a1[j] += h2f((u16)(hv >> 16));
            }
    }
#pragma unroll
    for (int j = 0; j < 3; j++) {
        int c = 2 * cw[j];
        if (c < EMB)
            fm[(size_t)f * EMB + c] = (end > beg) ? (a0[j] * inv * scv[c] + scv[320 + c]) : 0.f;
        if (c + 1 < EMB)
            fm[(size_t)f * EMB + c + 1] = (end > beg) ? (a1[j] * inv * scv[c + 1] + scv[321 + c]) : 0.f;
    }
}

// ---------------- head ----------------
static __global__ void k_build_out(const u16* __restrict__ h, const float* __restrict__ fm,
                                   const int* __restrict__ didx, const int* __restrict__ fb,
                                   const float* __restrict__ scv, u16* __restrict__ outb16) {
    int idx = blockIdx.x * 256 + threadIdx.x;
    if (idx >= ND * 640) return;
    int d = idx / 640, c = idx - d * 640;
    int n = didx[d];
    float v = 0.f;
    if (c < EMB)          v = (h2f(h[(size_t)n * 320 + c]) * scv[c] + scv[320 + c]) * (1.f / EMB);
    else if (c < 2 * EMB) v = fm[(size_t)fb[n] * EMB + (c - EMB)] * (1.f / EMB);
    outb16[idx] = f2h(v);
}

// bucket edges by pattern p=dea0*3+dea1; build padded row list + tile map
static __global__ void k_bucket(const int* __restrict__ dea, int* __restrict__ eord,
                                int* __restrict__ tm, int* __restrict__ ntl) {
    __shared__ int cnt[9], off[9], cur[9];
    __shared__ short pe[DD];
    int tid = threadIdx.x;
    for (int i = tid; i < 768; i += 256) eord[i] = -1;
    if (tid < 9) { cnt[tid] = 0; cur[tid] = 0; }
    __syncthreads();
    for (int e = tid; e < DD; e += 256) {
        int p = dea[2 * e] * 3 + dea[2 * e + 1];
        pe[e] = (short)p;
        atomicAdd(&cnt[p], 1);
    }
    __syncthreads();
    if (tid == 0) {
        int o = 0, tt = 0;
        for (int p = 0; p < 9; p++) {
            off[p] = o;
            int nt = (cnt[p] + 15) >> 4;
            for (int t = 0; t < nt; t++) { tm[2 * tt] = p; tm[2 * tt + 1] = o + 16 * t; tt++; }
            o += nt * 16;
        }
        *ntl = tt;
    }
    __syncthreads();
    for (int e = tid; e < DD; e += 256) {
        int p = pe[e];
        int slot = off[p] + atomicAdd(&cur[p], 1);
        eord[slot] = e;
    }
}

// gather V rows (outb16[dei0[d]]) into bucket-ordered Vg [768][640]
static __global__ void k_vgather(const u16* __restrict__ outb16, const int* __restrict__ eord,
                                 const int* __restrict__ dei, u16* __restrict__ Vg) {
    int idx = blockIdx.x * 256 + threadIdx.x;
    if (idx >= 768 * 80) return;                 // 80 x 16B = full 640-u16 row
    int slot = idx / 80, cb = idx - slot * 80;
    int d = eord[slot];
    uint4 v = {0u, 0u, 0u, 0u};
    if (d >= 0) v = *(const uint4*)&outb16[(size_t)dei[d] * 640 + cb * 8];
    *(uint4*)&Vg[(size_t)slot * 640 + cb * 8] = v;
}

// o0[d] = Vg_row @ Mpt[p]^T : 16-row MFMA tiles, K=640, N=640
static __global__ __launch_bounds__(256) void k_out0m(
        const u16* __restrict__ Vg, const u16* __restrict__ Mpt,
        const int* __restrict__ tm, const int* __restrict__ ntl,
        const int* __restrict__ eord, float* __restrict__ o0) {
    int bx = blockIdx.x;
    if (bx >= *ntl) return;
    int p = tm[2 * bx], row0 = tm[2 * bx + 1];
    __shared__ __align__(16) u16 sA[16 * 32];
    __shared__ __align__(16) u16 sB[640 * 32];
    int tid = threadIdx.x, lane = tid & 63, wv = tid >> 6;
    const u16* Bb = Mpt + (size_t)p * 640 * 640;
    f32x4 acc[10];
#pragma unroll
    for (int j = 0; j < 10; j++) { acc[j][0]=0.f; acc[j][1]=0.f; acc[j][2]=0.f; acc[j][3]=0.f; }
    int lrow = lane & 15, lcb = lane >> 4;
    for (int ks = 0; ks < 20; ks++) {
        int kk = ks * 32;
        __syncthreads();
        if (tid < 64) {
            int row = tid >> 2, cb = tid & 3;
            *(uint4*)&sA[loff(row, cb)] = *(const uint4*)&Vg[(size_t)(row0 + row) * 640 + kk + cb * 8];
        }
#pragma unroll
        for (int j = 0; j < 10; j++) {
            int i = tid + j * 256, row = i >> 2, cb = i & 3;
            *(uint4*)&sB[loff(row, cb)] = *(const uint4*)&Bb[(size_t)row * 640 + kk + cb * 8];
        }
        __syncthreads();
        f16x8 af = *(const f16x8*)&sA[loff(lrow, lcb)];
#pragma unroll
        for (int nf = 0; nf < 10; nf++) {
            f16x8 bf = *(const f16x8*)&sB[loff(wv * 160 + nf * 16 + lrow, lcb)];
            acc[nf] = __builtin_amdgcn_mfma_f32_16x16x32_f16(af, bf, acc[nf], 0, 0, 0);
        }
    }
    int lrow4 = (lane >> 4) * 4, lcol = lane & 15;
#pragma unroll
    for (int nf = 0; nf < 10; nf++) {
        int col = wv * 160 + nf * 16 + lcol;
#pragma unroll
        for (int rg = 0; rg < 4; rg++) {
            int row = lrow4 + rg;
            int e = eord[row0 + row];
            if (e >= 0 && col < HID) o0[(size_t)e * 640 + col] = acc[nf][rg];
        }
    }
}

static __global__ void k_logits(const float* __restrict__ o0, const u16* __restrict__ outb16,
                                const int* __restrict__ dei, float* __restrict__ dout) {
    int d = blockIdx.x;
    int tid = threadIdx.x, lane = tid & 63;
    int which = tid >> 6;
    int dsel = which ? (d + DD - 1) % DD : d;
    const float* a = o0 + (size_t)d * 640;
    const u16* bv = outb16 + (size_t)dei[DD + dsel] * 640;
    float s = 0.f;
    for (int c = lane; c < HID; c += 64) s += a[c] * h2f(bv[c]);
    for (int o = 32; o > 0; o >>= 1) s += __shfl_down(s, o);
    if (lane == 0) dout[which ? DD + d : d] = s;
}

extern "C" void kernel_launch(void* const* d_in, const int* in_sizes, int n_in,
                              void* d_out, int out_size, void* d_ws, size_t ws_size,
                              hipStream_t stream) {
    const int* x    = (const int*)d_in[0];
    const int* ei   = (const int*)d_in[1];
    const int* ea   = (const int*)d_in[2];
    const int* didx = (const int*)d_in[3];
    const int* fb   = (const int*)d_in[4];
    const int* dei  = (const int*)d_in[5];
    const int* dea  = (const int*)d_in[6];
    const float* ae1 = (const float*)d_in[7];
    const float* ae2 = (const float*)d_in[8];
    const float* ge1 = (const float*)d_in[9];
    const float* ge2 = (const float*)d_in[10];
    const float* W1  = (const float*)d_in[11];
    const float* b1  = (const float*)d_in[12];
    const float* W2  = (const float*)d_in[13];
    const float* b2  = (const float*)d_in[14];
    const float* bng = (const float*)d_in[15];
    const float* bnb = (const float*)d_in[16];
    const float* E1  = (const float*)d_in[17];
    const float* E2  = (const float*)d_in[18];
    float* dout = (float*)d_out;

    char* w = (char*)d_ws;
    auto alloc = [&](size_t bytes) -> void* {
        void* p = (void*)w;
        w += (bytes + 255) & ~(size_t)255;
        return p;
    };
    u16* h   = (u16*)alloc((size_t)MPAD * 320 * 2);      // 64.1 MB
    u16* ag  = (u16*)alloc((size_t)MPAD * 320 * 2);      // 64.1 MB
    u16* t   = (u16*)alloc((size_t)TCH * 640 * 2);       // 64.2 MB (overlaid by tail bufs)
    u16* W1p = (u16*)alloc((size_t)NL * 640 * 320 * 2);  //  2.1 MB
    u16* W2p = (u16*)alloc((size_t)NL * 384 * 640 * 2);  //  2.5 MB
    u16* Mpt = (u16*)alloc((size_t)9 * 640 * 640 * 2);   //  7.4 MB
    float* b1p = (float*)alloc((size_t)NL * 640 * 4);
    float* b2p = (float*)alloc((size_t)NL * 384 * 4);
    int* rowptr = (int*)alloc((size_t)(NN + 1) * 4);
    int* cursor = (int*)alloc((size_t)NN * 4);
    int* col    = (int*)alloc((size_t)EE * 4);
    int* deg    = (int*)alloc((size_t)NN * 4);
    int* cnt1   = (int*)alloc((size_t)NN * 3 * 4);
    int* cnt2   = (int*)alloc((size_t)NN * 3 * 4);
    int* incl   = (int*)alloc((size_t)NN * 4);
    int* bsum   = (int*)alloc(4096);
    int* boff   = (int*)alloc(4096);
    int* fcnt   = (int*)alloc((size_t)FF * 4);
    int* fstart = (int*)alloc((size_t)(FF + 1) * 4);
    float* colsum = (float*)alloc(384 * 4);
    float* colsq  = (float*)alloc(384 * 4);
    float* scv    = (float*)alloc(640 * 4);
    int* eord = (int*)alloc(768 * 4);
    int* tm   = (int*)alloc(96 * 4);
    int* ntl  = (int*)alloc(256);
    // tail buffers overlay t (dead after last gemm2): ~17.2 MB < 64.2 MB
    char* ov = (char*)t;
    auto oalloc = [&](size_t bytes) -> void* {
        void* p = (void*)ov;
        ov += (bytes + 255) & ~(size_t)255;
        return p;
    };
    float* fragmean = (float*)oalloc((size_t)FF * EMB * 4);
    u16* outb16     = (u16*)oalloc((size_t)ND * 640 * 2);
    float* o0       = (float*)oalloc((size_t)DD * 640 * 4);
    u16* Vg         = (u16*)oalloc((size_t)768 * 640 * 2);

    hipMemsetAsync(deg, 0, (size_t)NN * 4, stream);
    hipMemsetAsync(cnt1, 0, (size_t)NN * 3 * 4, stream);
    hipMemsetAsync(cnt2, 0, (size_t)NN * 3 * 4, stream);
    hipMemsetAsync(fcnt, 0, (size_t)FF * 4, stream);

    k_packW1<<<(NL * 640 * 320 + 255) / 256, 256, 0, stream>>>(W1, W1p);
    k_packW2<<<(NL * 384 * 640 + 255) / 256, 256, 0, stream>>>(W2, W2p);
    k_packb<<<(NL * (640 + 384) + 255) / 256, 256, 0, stream>>>(b1, b2, b1p, b2p);
    k_precompMt<<<dim3(9, 20, 20), 256, 0, stream>>>(E1, E2, Mpt);
    k_bucket<<<1, 256, 0, stream>>>(dea, eord, tm, ntl);

    k_init_h<<<(NN * 160 + 255) / 256, 256, 0, stream>>>(x, ae1, ae2, (uint32_t*)h);
    k_count<<<(EE + 255) / 256, 256, 0, stream>>>(ei, ea, deg, cnt1, cnt2);

    int nb = (NN + 255) / 256;
    k_scan1<<<nb, 256, 0, stream>>>(deg, incl, bsum, NN);
    k_scan2<<<1, 1024, 0, stream>>>(bsum, boff, nb);
    k_scan3<<<nb, 256, 0, stream>>>(deg, incl, boff, rowptr, cursor, NN);
    k_scatter<<<(EE + 255) / 256, 256, 0, stream>>>(ei, cursor, col);

    k_fragcnt<<<nb, 256, 0, stream>>>(fb, fcnt);
    int nbf = (FF + 255) / 256;
    k_scan1<<<nbf, 256, 0, stream>>>(fcnt, incl, bsum, FF);
    k_scan2<<<1, 1024, 0, stream>>>(bsum, boff, nbf);
    k_scan3<<<nbf, 256, 0, stream>>>(fcnt, incl, boff, fstart, (int*)nullptr, FF);

    for (int l = 0; l < NL; l++) {
        const float* ge1l = ge1 + (size_t)l * 6 * EMB;
        const float* ge2l = ge2 + (size_t)l * 3 * EMB;
        k_aggr<<<2048, 256, 0, stream>>>(h, ag, rowptr, col, cnt1, cnt2, ge1l, ge2l,
                                         (l == 0) ? nullptr : scv, (l == 0) ? 0 : 1);
        hipMemsetAsync(colsum, 0, 384 * 4, stream);
        hipMemsetAsync(colsq, 0, 384 * 4, stream);
        for (int c0 = 0; c0 < NN; c0 += TCH) {
            int Mc = (NN - c0 < TCH) ? (NN - c0) : TCH;
            int mt1 = (Mc + 127) / 128;
            k_mfma1<<<dim3(2, mt1), 512, 0, stream>>>(
                ag + (size_t)c0 * 320, W1p + (size_t)l * 640 * 320, b1p + l * 640, t);
            int mt2 = (Mc + 63) / 64;
            k_mfma2<<<dim3(3, mt2), 256, 0, stream>>>(
                t, W2p + (size_t)l * 384 * 640, b2p + l * 384,
                h + (size_t)c0 * 320, Mc, colsum, colsq);
        }
        k_bnfinal<<<1, 320, 0, stream>>>(colsum, colsq, bng + (size_t)l * EMB, bnb + (size_t)l * EMB, scv);
    }

    k_fragmean<<<(FF + 3) / 4, 256, 0, stream>>>(h, fstart, scv, fragmean);
    k_build_out<<<(ND * 640 + 255) / 256, 256, 0, stream>>>(h, fragmean, didx, fb, scv, outb16);
    k_vgather<<<(768 * 80 + 255) / 256, 256, 0, stream>>>(outb16, eord, dei, Vg);
    k_out0m<<<48, 256, 0, stream>>>(Vg, Mpt, tm, ntl, eord, o0);
    k_logits<<<DD, 128, 0, stream>>>(o0, outb16, dei, dout);
}

// Round 15
// 1765.700 us; speedup vs baseline: 1.2731x; 1.2731x over previous
//
#include <hip/hip_runtime.h>
#include <hip/hip_bf16.h>
#include <stdint.h>

#define NN 100000
#define EE 400000
#define ND 4096
#define DD 512
#define FF 8000
#define EMB 300
#define HID 600
#define NL 5
#define TCH 50176     // M-chunk rows, 2 chunks
#define MPAD 100096

typedef unsigned short u16;
typedef _Float16 f16x8 __attribute__((ext_vector_type(8)));
typedef float f32x4 __attribute__((ext_vector_type(4)));
typedef float f32x2 __attribute__((ext_vector_type(2)));

static __device__ inline u16 f2h(float v) {
    union { _Float16 h; u16 u; } c; c.h = (_Float16)v; return c.u;
}
static __device__ inline float h2f(u16 u) {
    union { u16 u; _Float16 h; } c; c.u = u; return (float)c.h;
}
static __device__ inline uint32_t pk2(float a, float b) {
    return (uint32_t)f2h(a) | ((uint32_t)f2h(b) << 16);
}
static __device__ inline f32x2 up2(uint32_t w) {
    f32x2 r; r.x = h2f((u16)(w & 0xffff)); r.y = h2f((u16)(w >> 16)); return r;
}
// LDS XOR swizzle: 16B block cb of row -> cb ^ ((row>>1)&3); frag reads 2-way (free)
static __device__ inline int loff(int row, int cb) {
    return row * 32 + ((cb ^ (((row) >> 1) & 3)) * 8);
}

// ---------------- node feature init (fp16, pad cols zeroed) ----------------
static __global__ void k_init_h(const int* __restrict__ x, const float* __restrict__ ae1,
                                const float* __restrict__ ae2, uint32_t* __restrict__ h) {
    int idx = blockIdx.x * 256 + threadIdx.x;
    if (idx >= NN * 160) return;
    int n = idx / 160, cw = idx - n * 160;
    int c = 2 * cw;
    int x0 = x[2 * n], x1 = x[2 * n + 1];
    float v0 = 0.f, v1 = 0.f;
    if (c < EMB)     v0 = ae1[x0 * EMB + c] + ae2[x1 * EMB + c];
    if (c + 1 < EMB) v1 = ae1[x0 * EMB + c + 1] + ae2[x1 * EMB + c + 1];
    h[idx] = pk2(v0, v1);
}

// ---------------- degree + edge-attr histograms ----------------
static __global__ void k_count(const int* __restrict__ ei, const int* __restrict__ ea,
                               int* __restrict__ deg, int* __restrict__ cnt1, int* __restrict__ cnt2) {
    int e = blockIdx.x * 256 + threadIdx.x;
    if (e >= EE) return;
    int dst = ei[EE + e];
    atomicAdd(&deg[dst], 1);
    atomicAdd(&cnt1[dst * 3 + ea[2 * e]], 1);
    atomicAdd(&cnt2[dst * 3 + ea[2 * e + 1]], 1);
}

// ---------------- generic 3-pass exclusive scan ----------------
static __global__ void k_scan1(const int* __restrict__ in, int* __restrict__ incl,
                               int* __restrict__ bsum, int L) {
    __shared__ int s[256];
    int t = threadIdx.x, i = blockIdx.x * 256 + t;
    int v = (i < L) ? in[i] : 0;
    s[t] = v; __syncthreads();
    for (int o = 1; o < 256; o <<= 1) {
        int xv = (t >= o) ? s[t - o] : 0; __syncthreads();
        s[t] += xv; __syncthreads();
    }
    if (i < L) incl[i] = s[t];
    if (t == 255) bsum[blockIdx.x] = s[255];
}

static __global__ void k_scan2(const int* __restrict__ bsum, int* __restrict__ boff, int nb) {
    __shared__ int s[1024];
    int t = threadIdx.x;
    int v = (t < nb) ? bsum[t] : 0;
    s[t] = v; __syncthreads();
    for (int o = 1; o < 1024; o <<= 1) {
        int xv = (t >= o) ? s[t - o] : 0; __syncthreads();
        s[t] += xv; __syncthreads();
    }
    if (t < nb) boff[t] = s[t] - v;
}

static __global__ void k_scan3(const int* __restrict__ in, const int* __restrict__ incl,
                               const int* __restrict__ boff, int* __restrict__ op,
                               int* __restrict__ cursor, int L) {
    int i = blockIdx.x * 256 + threadIdx.x;
    if (i >= L) return;
    int ex = incl[i] - in[i] + boff[i / 256];
    op[i] = ex;
    if (cursor) cursor[i] = ex;
    if (i == L - 1) op[L] = ex + in[i];
}

// ---------------- CSR scatter ----------------
static __global__ void k_scatter(const int* __restrict__ ei, int* __restrict__ cursor,
                                 int* __restrict__ col) {
    int e = blockIdx.x * 256 + threadIdx.x;
    if (e >= EE) return;
    int dst = ei[EE + e], src = ei[e];
    int p = atomicAdd(&cursor[dst], 1);
    col[p] = src;
}

// ---------------- GIN aggregation: grid-stride, 4-way unrolled gathers --------
static __global__ void k_aggr(const u16* __restrict__ h, u16* __restrict__ ag,
                              const int* __restrict__ rowptr, const int* __restrict__ col,
                              const int* __restrict__ cnt1, const int* __restrict__ cnt2,
                              const float* __restrict__ ge1l, const float* __restrict__ ge2l,
                              const float* __restrict__ scv, int relu) {
    __shared__ float se[7 * 320];
    for (int idx = threadIdx.x; idx < 7 * 320; idx += 256) {
        int g = idx / 320, c = idx - g * 320;
        float v = 0.f;
        if (c < EMB) {
            if (g < 3) v = ge1l[g * EMB + c];
            else if (g < 6) v = ge2l[(g - 3) * EMB + c];
            else v = ge1l[4 * EMB + c] + ge2l[c];
        }
        se[idx] = v;
    }
    __syncthreads();
    int wv = threadIdx.x >> 6, lane = threadIdx.x & 63;

    int cw[3];
    f32x2 sc2[3], sh2[3];
#pragma unroll
    for (int j = 0; j < 3; j++) {
        cw[j] = lane + 64 * j;
        if (cw[j] < 160) {
            int c = 2 * cw[j];
            if (scv) {
                sc2[j] = *(const f32x2*)&scv[c];
                sh2[j] = *(const f32x2*)&scv[320 + c];
            } else { sc2[j] = (f32x2){1.f, 1.f}; sh2[j] = (f32x2){0.f, 0.f}; }
        }
    }

    for (int g0 = blockIdx.x * 4; g0 < NN; g0 += gridDim.x * 4) {
        int n = g0 + wv;
        if (n >= NN) continue;
        float c1a = (float)cnt1[n * 3], c1b = (float)cnt1[n * 3 + 1], c1c = (float)cnt1[n * 3 + 2];
        float c2a = (float)cnt2[n * 3], c2b = (float)cnt2[n * 3 + 1], c2c = (float)cnt2[n * 3 + 2];

        f32x2 acc[3];
        const uint32_t* hn = (const uint32_t*)(h + (size_t)n * 320);
#pragma unroll
        for (int j = 0; j < 3; j++) {
            if (cw[j] < 160) {
                int c = 2 * cw[j];
                f32x2 v = up2(hn[cw[j]]) * sc2[j] + sh2[j];
                if (relu) { v.x = fmaxf(v.x, 0.f); v.y = fmaxf(v.y, 0.f); }
                acc[j] = v + *(const f32x2*)&se[6 * 320 + c]
                       + c1a * *(const f32x2*)&se[c]
                       + c1b * *(const f32x2*)&se[320 + c]
                       + c1c * *(const f32x2*)&se[640 + c]
                       + c2a * *(const f32x2*)&se[960 + c]
                       + c2b * *(const f32x2*)&se[1280 + c]
                       + c2c * *(const f32x2*)&se[1600 + c];
            }
        }
        int p = rowptr[n], end = rowptr[n + 1];
        for (; p + 4 <= end; p += 4) {
            const uint32_t* h0 = (const uint32_t*)(h + (size_t)col[p] * 320);
            const uint32_t* h1 = (const uint32_t*)(h + (size_t)col[p + 1] * 320);
            const uint32_t* h2 = (const uint32_t*)(h + (size_t)col[p + 2] * 320);
            const uint32_t* h3 = (const uint32_t*)(h + (size_t)col[p + 3] * 320);
            uint32_t w0[3], w1[3], w2[3], w3[3];
#pragma unroll
            for (int j = 0; j < 3; j++) {
                if (cw[j] < 160) {
                    w0[j] = h0[cw[j]]; w1[j] = h1[cw[j]];
                    w2[j] = h2[cw[j]]; w3[j] = h3[cw[j]];
                }
            }
#pragma unroll
            for (int j = 0; j < 3; j++) {
                if (cw[j] < 160) {
                    f32x2 v0 = up2(w0[j]) * sc2[j] + sh2[j];
                    if (relu) { v0.x = fmaxf(v0.x, 0.f); v0.y = fmaxf(v0.y, 0.f); }
                    acc[j] += v0;
                    f32x2 v1 = up2(w1[j]) * sc2[j] + sh2[j];
                    if (relu) { v1.x = fmaxf(v1.x, 0.f); v1.y = fmaxf(v1.y, 0.f); }
                    acc[j] += v1;
                    f32x2 v2 = up2(w2[j]) * sc2[j] + sh2[j];
                    if (relu) { v2.x = fmaxf(v2.x, 0.f); v2.y = fmaxf(v2.y, 0.f); }
                    acc[j] += v2;
                    f32x2 v3 = up2(w3[j]) * sc2[j] + sh2[j];
                    if (relu) { v3.x = fmaxf(v3.x, 0.f); v3.y = fmaxf(v3.y, 0.f); }
                    acc[j] += v3;
                }
            }
        }
        for (; p + 2 <= end; p += 2) {
            const uint32_t* h0 = (const uint32_t*)(h + (size_t)col[p] * 320);
            const uint32_t* h1 = (const uint32_t*)(h + (size_t)col[p + 1] * 320);
            uint32_t w0[3], w1[3];
#pragma unroll
            for (int j = 0; j < 3; j++)
                if (cw[j] < 160) { w0[j] = h0[cw[j]]; w1[j] = h1[cw[j]]; }
#pragma unroll
            for (int j = 0; j < 3; j++) {
                if (cw[j] < 160) {
                    f32x2 v0 = up2(w0[j]) * sc2[j] + sh2[j];
                    if (relu) { v0.x = fmaxf(v0.x, 0.f); v0.y = fmaxf(v0.y, 0.f); }
                    acc[j] += v0;
                    f32x2 v1 = up2(w1[j]) * sc2[j] + sh2[j];
                    if (relu) { v1.x = fmaxf(v1.x, 0.f); v1.y = fmaxf(v1.y, 0.f); }
                    acc[j] += v1;
                }
            }
        }
        for (; p < end; ++p) {
            const uint32_t* hr = (const uint32_t*)(h + (size_t)col[p] * 320);
#pragma unroll
            for (int j = 0; j < 3; j++) {
                if (cw[j] < 160) {
                    f32x2 v = up2(hr[cw[j]]) * sc2[j] + sh2[j];
                    if (relu) { v.x = fmaxf(v.x, 0.f); v.y = fmaxf(v.y, 0.f); }
                    acc[j] += v;
                }
            }
        }
        uint32_t* ao = (uint32_t*)(ag + (size_t)n * 320);
#pragma unroll
        for (int j = 0; j < 3; j++)
            if (cw[j] < 160) ao[cw[j]] = pk2(acc[j].x, acc[j].y);
    }
}

// ---------------- weight packing: transposed, padded, fp16 ------------
static __global__ void k_packW1(const float* __restrict__ W1, u16* __restrict__ W1p) {
    int idx = blockIdx.x * 256 + threadIdx.x;
    const int per = 640 * 320;
    if (idx >= NL * per) return;
    int l = idx / per, rem = idx % per;
    int n = rem / 320, k = rem % 320;
    float v = (k < EMB && n < HID) ? W1[(size_t)l * EMB * HID + (size_t)k * HID + n] : 0.f;
    W1p[idx] = f2h(v);
}

static __global__ void k_packW2(const float* __restrict__ W2, u16* __restrict__ W2p) {
    int idx = blockIdx.x * 256 + threadIdx.x;
    const int per = 384 * 640;
    if (idx >= NL * per) return;
    int l = idx / per, rem = idx % per;
    int n = rem / 640, k = rem % 640;
    float v = (k < HID && n < EMB) ? W2[(size_t)l * HID * EMB + (size_t)k * EMB + n] : 0.f;
    W2p[idx] = f2h(v);
}

static __global__ void k_packb(const float* __restrict__ b1, const float* __restrict__ b2,
                               float* __restrict__ b1p, float* __restrict__ b2p) {
    int idx = blockIdx.x * 256 + threadIdx.x;
    if (idx < NL * 640) {
        int l = idx / 640, n = idx % 640;
        b1p[idx] = (n < HID) ? b1[l * HID + n] : 0.f;
    } else if (idx < NL * 640 + NL * 384) {
        int j = idx - NL * 640;
        int l = j / 384, n = j % 384;
        b2p[j] = (n < EMB) ? b2[l * EMB + n] : 0.f;
    }
}

// Mpt[p][m][k] = fp16(E1[a][k*600+m] + E2[b][k*600+m]), 640x640 zero-padded
static __global__ void k_precompMt(const float* __restrict__ E1, const float* __restrict__ E2,
                                   u16* __restrict__ Mpt) {
    __shared__ float sT[32][33];
    int p = blockIdx.x, mt = blockIdx.y, kt = blockIdx.z;
    int a = p / 3, b = p % 3;
    const float* e1 = E1 + (size_t)a * 360000;
    const float* e2 = E2 + (size_t)b * 360000;
    int tx = threadIdx.x & 31, ty = threadIdx.x >> 5;
#pragma unroll
    for (int it = 0; it < 4; it++) {
        int k = kt * 32 + ty + it * 8;
        int m = mt * 32 + tx;
        float v = 0.f;
        if (k < HID && m < HID) v = e1[k * HID + m] + e2[k * HID + m];
        sT[ty + it * 8][tx] = v;
    }
    __syncthreads();
#pragma unroll
    for (int it = 0; it < 4; it++) {
        int m = mt * 32 + ty + it * 8;
        int k = kt * 32 + tx;
        Mpt[(size_t)p * 640 * 640 + (size_t)m * 640 + k] = f2h(sT[tx][ty + it * 8]);
    }
}

// ---------------- MFMA GEMM (round-7 reg-staged, 2D grid) ------------------
// MODE 1: t = relu(ag@W1p+b1) fp16.  BM=128, BN=128, K=320. grid (5, M/128)
// MODE 2: h = t@W2p+b2 fp16 + fused BN stats. BM=64, BN=128, K=640. grid (3, M/64)
template <int MODE>
static __global__ __launch_bounds__(256) void k_mfma(
        const u16* __restrict__ A, const u16* __restrict__ B,
        const float* __restrict__ bias, u16* __restrict__ Out, int Mc,
        float* __restrict__ colsum, float* __restrict__ colsq) {
    constexpr int BM    = (MODE == 1) ? 128 : 64;
    constexpr int STR   = (MODE == 1) ? 320 : 640;
    constexpr int STRO  = (MODE == 1) ? 640 : 320;
    constexpr int NSTEP = (MODE == 1) ? 10 : 20;
    constexpr int MF = 4;
    constexpr int NF = (MODE == 1) ? 4 : 2;

    __shared__ __align__(16) u16 sA[BM * 32];
    __shared__ __align__(16) u16 sB[128 * 32];

    int tid = threadIdx.x;
    int lane = tid & 63, wv = tid >> 6;
    int wm = (MODE == 1) ? (wv >> 1) : 0;
    int wn = (MODE == 1) ? (wv & 1) : wv;
    int m0 = blockIdx.y * BM;
    int n0 = blockIdx.x * 128;
    int sr = tid >> 2, scb = tid & 3;

    uint4 rA0, rA1, rB0, rB1;
    auto do_load = [&](int ks) {
        int kk = ks * 32;
        const u16* as = A + (size_t)(m0 + sr) * STR + kk + scb * 8;
        rA0 = *(const uint4*)as;
        if (MODE == 1) rA1 = *(const uint4*)(as + (size_t)64 * STR);
        const u16* bs = B + (size_t)(n0 + sr) * STR + kk + scb * 8;
        rB0 = *(const uint4*)bs;
        rB1 = *(const uint4*)(bs + (size_t)64 * STR);
    };
    do_load(0);

    f32x4 acc[MF][NF];
#pragma unroll
    for (int i = 0; i < MF; i++)
#pragma unroll
        for (int j = 0; j < NF; j++) {
            acc[i][j][0] = 0.f; acc[i][j][1] = 0.f; acc[i][j][2] = 0.f; acc[i][j][3] = 0.f;
        }

    int lrow = lane & 15, lcb = lane >> 4;
    for (int ks = 0; ks < NSTEP; ++ks) {
        __syncthreads();
        *(uint4*)&sA[loff(sr, scb)] = rA0;
        if (MODE == 1) *(uint4*)&sA[loff(sr + 64, scb)] = rA1;
        *(uint4*)&sB[loff(sr, scb)] = rB0;
        *(uint4*)&sB[loff(sr + 64, scb)] = rB1;
        __syncthreads();
        if (ks + 1 < NSTEP) do_load(ks + 1);
        f16x8 af[MF], bfr[NF];
#pragma unroll
        for (int mf = 0; mf < MF; ++mf) {
            int r = wm * 64 + mf * 16 + lrow;
            af[mf] = *(const f16x8*)&sA[loff(r, lcb)];
        }
#pragma unroll
        for (int nf = 0; nf < NF; ++nf) {
            int r = wn * (NF * 16) + nf * 16 + lrow;
            bfr[nf] = *(const f16x8*)&sB[loff(r, lcb)];
        }
#pragma unroll
        for (int mf = 0; mf < MF; ++mf)
#pragma unroll
            for (int nf = 0; nf < NF; ++nf)
                acc[mf][nf] = __builtin_amdgcn_mfma_f32_16x16x32_f16(af[mf], bfr[nf], acc[mf][nf], 0, 0, 0);
    }

    int lrow4 = (lane >> 4) * 4, lcol = lane & 15;
    if (MODE == 1) {
#pragma unroll
        for (int mf = 0; mf < MF; ++mf)
#pragma unroll
            for (int nf = 0; nf < NF; ++nf) {
                int colg = n0 + wn * 64 + nf * 16 + lcol;
                float bv = bias[colg];
#pragma unroll
                for (int rg = 0; rg < 4; ++rg) {
                    int rowl = m0 + wm * 64 + mf * 16 + lrow4 + rg;
                    float v = fmaxf(acc[mf][nf][rg] + bv, 0.f);
                    Out[(size_t)rowl * STRO + colg] = f2h(v);
                }
            }
    } else {
#pragma unroll
        for (int nf = 0; nf < NF; ++nf) {
            int colg = n0 + wn * 32 + nf * 16 + lcol;
            float bv = bias[colg];
            float s = 0.f, q = 0.f;
#pragma unroll
            for (int mf = 0; mf < MF; ++mf)
#pragma unroll
                for (int rg = 0; rg < 4; ++rg) {
                    int rowl = m0 + mf * 16 + lrow4 + rg;
                    float v = acc[mf][nf][rg] + bv;
                    if (rowl < Mc) {
                        s += v; q += v * v;
                        if (colg < EMB) Out[(size_t)rowl * STRO + colg] = f2h(v);
                    }
                }
            s += __shfl_xor(s, 16); s += __shfl_xor(s, 32);
            q += __shfl_xor(q, 16); q += __shfl_xor(q, 32);
            if (lane < 16) { atomicAdd(&colsum[colg], s); atomicAdd(&colsq[colg], q); }
        }
    }
}

// ---------------- BN scale/shift (pad cols -> 0) ----------------
static __global__ void k_bnfinal(const float* __restrict__ colsum, const float* __restrict__ colsq,
                                 const float* __restrict__ g, const float* __restrict__ b,
                                 float* __restrict__ scv) {
    int c = threadIdx.x;
    if (c >= 320) return;
    if (c >= EMB) { scv[c] = 0.f; scv[320 + c] = 0.f; return; }
    float mean = colsum[c] * (1.f / NN);
    float var = colsq[c] * (1.f / NN) - mean * mean;
    float rs = rsqrtf(var + 1e-5f);
    float sc = rs * g[c];
    scv[c] = sc;
    scv[320 + c] = b[c] - mean * sc;
}

// ---------------- fragment pooling (applies final BN after mean) ----------------
static __global__ void k_fragcnt(const int* __restrict__ fb, int* __restrict__ fcnt) {
    int i = blockIdx.x * 256 + threadIdx.x;
    if (i >= NN) return;
    atomicAdd(&fcnt[fb[i]], 1);
}

static __global__ void k_fragmean(const u16* __restrict__ h, const int* __restrict__ fstart,
                                  const float* __restrict__ scv, float* __restrict__ fm) {
    int wv = threadIdx.x >> 6, lane = threadIdx.x & 63;
    int f = blockIdx.x * 4 + wv;
    if (f >= FF) return;
    int beg = fstart[f], end = fstart[f + 1];
    float inv = (end > beg) ? 1.f / (float)(end - beg) : 0.f;
    float a0[3], a1[3]; int cw[3];
#pragma unroll
    for (int j = 0; j < 3; j++) { cw[j] = lane + 64 * j; a0[j] = 0.f; a1[j] = 0.f; }
    for (int r = beg; r < end; ++r) {
        const uint32_t* hr = (const uint32_t*)(h + (size_t)r * 320);
#pragma unroll
        for (int j = 0; j < 3; j++)
            if (cw[j] < 160) {
                uint32_t hv = hr[cw[j]];
                a0[j] += h2f((u16)(hv & 0xffff)); a1[j] += h2f((u16)(hv >> 16));
            }
    }
#pragma unroll
    for (int j = 0; j < 3; j++) {
        int c = 2 * cw[j];
        if (c < EMB)
            fm[(size_t)f * EMB + c] = (end > beg) ? (a0[j] * inv * scv[c] + scv[320 + c]) : 0.f;
        if (c + 1 < EMB)
            fm[(size_t)f * EMB + c + 1] = (end > beg) ? (a1[j] * inv * scv[c + 1] + scv[321 + c]) : 0.f;
    }
}

// ---------------- head ----------------
static __global__ void k_build_out(const u16* __restrict__ h, const float* __restrict__ fm,
                                   const int* __restrict__ didx, const int* __restrict__ fb,
                                   const float* __restrict__ scv, u16* __restrict__ outb16) {
    int idx = blockIdx.x * 256 + threadIdx.x;
    if (idx >= ND * 640) return;
    int d = idx / 640, c = idx - d * 640;
    int n = didx[d];
    float v = 0.f;
    if (c < EMB)          v = (h2f(h[(size_t)n * 320 + c]) * scv[c] + scv[320 + c]) * (1.f / EMB);
    else if (c < 2 * EMB) v = fm[(size_t)fb[n] * EMB + (c - EMB)] * (1.f / EMB);
    outb16[idx] = f2h(v);
}

// bucket edges by pattern p=dea0*3+dea1; build padded row list + tile map
static __global__ void k_bucket(const int* __restrict__ dea, int* __restrict__ eord,
                                int* __restrict__ tm, int* __restrict__ ntl) {
    __shared__ int cnt[9], off[9], cur[9];
    __shared__ short pe[DD];
    int tid = threadIdx.x;
    for (int i = tid; i < 768; i += 256) eord[i] = -1;
    if (tid < 9) { cnt[tid] = 0; cur[tid] = 0; }
    __syncthreads();
    for (int e = tid; e < DD; e += 256) {
        int p = dea[2 * e] * 3 + dea[2 * e + 1];
        pe[e] = (short)p;
        atomicAdd(&cnt[p], 1);
    }
    __syncthreads();
    if (tid == 0) {
        int o = 0, tt = 0;
        for (int p = 0; p < 9; p++) {
            off[p] = o;
            int nt = (cnt[p] + 15) >> 4;
            for (int t = 0; t < nt; t++) { tm[2 * tt] = p; tm[2 * tt + 1] = o + 16 * t; tt++; }
            o += nt * 16;
        }
        *ntl = tt;
    }
    __syncthreads();
    for (int e = tid; e < DD; e += 256) {
        int p = pe[e];
        int slot = off[p] + atomicAdd(&cur[p], 1);
        eord[slot] = e;
    }
}

// gather V rows (outb16[dei0[d]]) into bucket-ordered Vg [768][640]
static __global__ void k_vgather(const u16* __restrict__ outb16, const int* __restrict__ eord,
                                 const int* __restrict__ dei, u16* __restrict__ Vg) {
    int idx = blockIdx.x * 256 + threadIdx.x;
    if (idx >= 768 * 80) return;                 // 80 x 16B = full 640-u16 row
    int slot = idx / 80, cb = idx - slot * 80;
    int d = eord[slot];
    uint4 v = {0u, 0u, 0u, 0u};
    if (d >= 0) v = *(const uint4*)&outb16[(size_t)dei[d] * 640 + cb * 8];
    *(uint4*)&Vg[(size_t)slot * 640 + cb * 8] = v;
}

// o0[d] = Vg_row @ Mpt[p]^T : 16-row MFMA tiles, K=640, N=640
static __global__ __launch_bounds__(256) void k_out0m(
        const u16* __restrict__ Vg, const u16* __restrict__ Mpt,
        const int* __restrict__ tm, const int* __restrict__ ntl,
        const int* __restrict__ eord, float* __restrict__ o0) {
    int bx = blockIdx.x;
    if (bx >= *ntl) return;
    int p = tm[2 * bx], row0 = tm[2 * bx + 1];
    __shared__ __align__(16) u16 sA[16 * 32];
    __shared__ __align__(16) u16 sB[640 * 32];
    int tid = threadIdx.x, lane = tid & 63, wv = tid >> 6;
    const u16* Bb = Mpt + (size_t)p * 640 * 640;
    f32x4 acc[10];
#pragma unroll
    for (int j = 0; j < 10; j++) { acc[j][0]=0.f; acc[j][1]=0.f; acc[j][2]=0.f; acc[j][3]=0.f; }
    int lrow = lane & 15, lcb = lane >> 4;
    for (int ks = 0; ks < 20; ks++) {
        int kk = ks * 32;
        __syncthreads();
        if (tid < 64) {
            int row = tid >> 2, cb = tid & 3;
            *(uint4*)&sA[loff(row, cb)] = *(const uint4*)&Vg[(size_t)(row0 + row) * 640 + kk + cb * 8];
        }
#pragma unroll
        for (int j = 0; j < 10; j++) {
            int i = tid + j * 256, row = i >> 2, cb = i & 3;
            *(uint4*)&sB[loff(row, cb)] = *(const uint4*)&Bb[(size_t)row * 640 + kk + cb * 8];
        }
        __syncthreads();
        f16x8 af = *(const f16x8*)&sA[loff(lrow, lcb)];
#pragma unroll
        for (int nf = 0; nf < 10; nf++) {
            f16x8 bf = *(const f16x8*)&sB[loff(wv * 160 + nf * 16 + lrow, lcb)];
            acc[nf] = __builtin_amdgcn_mfma_f32_16x16x32_f16(af, bf, acc[nf], 0, 0, 0);
        }
    }
    int lrow4 = (lane >> 4) * 4, lcol = lane & 15;
#pragma unroll
    for (int nf = 0; nf < 10; nf++) {
        int col = wv * 160 + nf * 16 + lcol;
#pragma unroll
        for (int rg = 0; rg < 4; rg++) {
            int row = lrow4 + rg;
            int e = eord[row0 + row];
            if (e >= 0 && col < HID) o0[(size_t)e * 640 + col] = acc[nf][rg];
        }
    }
}

static __global__ void k_logits(const float* __restrict__ o0, const u16* __restrict__ outb16,
                                const int* __restrict__ dei, float* __restrict__ dout) {
    int d = blockIdx.x;
    int tid = threadIdx.x, lane = tid & 63;
    int which = tid >> 6;
    int dsel = which ? (d + DD - 1) % DD : d;
    const float* a = o0 + (size_t)d * 640;
    const u16* bv = outb16 + (size_t)dei[DD + dsel] * 640;
    float s = 0.f;
    for (int c = lane; c < HID; c += 64) s += a[c] * h2f(bv[c]);
    for (int o = 32; o > 0; o >>= 1) s += __shfl_down(s, o);
    if (lane == 0) dout[which ? DD + d : d] = s;
}

extern "C" void kernel_launch(void* const* d_in, const int* in_sizes, int n_in,
                              void* d_out, int out_size, void* d_ws, size_t ws_size,
                              hipStream_t stream) {
    const int* x    = (const int*)d_in[0];
    const int* ei   = (const int*)d_in[1];
    const int* ea   = (const int*)d_in[2];
    const int* didx = (const int*)d_in[3];
    const int* fb   = (const int*)d_in[4];
    const int* dei  = (const int*)d_in[5];
    const int* dea  = (const int*)d_in[6];
    const float* ae1 = (const float*)d_in[7];
    const float* ae2 = (const float*)d_in[8];
    const float* ge1 = (const float*)d_in[9];
    const float* ge2 = (const float*)d_in[10];
    const float* W1  = (const float*)d_in[11];
    const float* b1  = (const float*)d_in[12];
    const float* W2  = (const float*)d_in[13];
    const float* b2  = (const float*)d_in[14];
    const float* bng = (const float*)d_in[15];
    const float* bnb = (const float*)d_in[16];
    const float* E1  = (const float*)d_in[17];
    const float* E2  = (const float*)d_in[18];
    float* dout = (float*)d_out;

    char* w = (char*)d_ws;
    auto alloc = [&](size_t bytes) -> void* {
        void* p = (void*)w;
        w += (bytes + 255) & ~(size_t)255;
        return p;
    };
    u16* h   = (u16*)alloc((size_t)MPAD * 320 * 2);      // 64.1 MB
    u16* ag  = (u16*)alloc((size_t)MPAD * 320 * 2);      // 64.1 MB
    u16* t   = (u16*)alloc((size_t)TCH * 640 * 2);       // 64.2 MB (overlaid by tail bufs)
    u16* W1p = (u16*)alloc((size_t)NL * 640 * 320 * 2);  //  2.1 MB
    u16* W2p = (u16*)alloc((size_t)NL * 384 * 640 * 2);  //  2.5 MB
    u16* Mpt = (u16*)alloc((size_t)9 * 640 * 640 * 2);   //  7.4 MB
    float* b1p = (float*)alloc((size_t)NL * 640 * 4);
    float* b2p = (float*)alloc((size_t)NL * 384 * 4);
    int* rowptr = (int*)alloc((size_t)(NN + 1) * 4);
    int* cursor = (int*)alloc((size_t)NN * 4);
    int* col    = (int*)alloc((size_t)EE * 4);
    int* deg    = (int*)alloc((size_t)NN * 4);
    int* cnt1   = (int*)alloc((size_t)NN * 3 * 4);
    int* cnt2   = (int*)alloc((size_t)NN * 3 * 4);
    int* incl   = (int*)alloc((size_t)NN * 4);
    int* bsum   = (int*)alloc(4096);
    int* boff   = (int*)alloc(4096);
    int* fcnt   = (int*)alloc((size_t)FF * 4);
    int* fstart = (int*)alloc((size_t)(FF + 1) * 4);
    float* colsum = (float*)alloc(384 * 4);
    float* colsq  = (float*)alloc(384 * 4);
    float* scv    = (float*)alloc(640 * 4);
    int* eord = (int*)alloc(768 * 4);
    int* tm   = (int*)alloc(96 * 4);
    int* ntl  = (int*)alloc(256);
    // tail buffers overlay t (dead after last gemm2): ~17.2 MB < 64.2 MB
    char* ov = (char*)t;
    auto oalloc = [&](size_t bytes) -> void* {
        void* p = (void*)ov;
        ov += (bytes + 255) & ~(size_t)255;
        return p;
    };
    float* fragmean = (float*)oalloc((size_t)FF * EMB * 4);
    u16* outb16     = (u16*)oalloc((size_t)ND * 640 * 2);
    float* o0       = (float*)oalloc((size_t)DD * 640 * 4);
    u16* Vg         = (u16*)oalloc((size_t)768 * 640 * 2);

    hipMemsetAsync(deg, 0, (size_t)NN * 4, stream);
    hipMemsetAsync(cnt1, 0, (size_t)NN * 3 * 4, stream);
    hipMemsetAsync(cnt2, 0, (size_t)NN * 3 * 4, stream);
    hipMemsetAsync(fcnt, 0, (size_t)FF * 4, stream);

    k_packW1<<<(NL * 640 * 320 + 255) / 256, 256, 0, stream>>>(W1, W1p);
    k_packW2<<<(NL * 384 * 640 + 255) / 256, 256, 0, stream>>>(W2, W2p);
    k_packb<<<(NL * (640 + 384) + 255) / 256, 256, 0, stream>>>(b1, b2, b1p, b2p);
    k_precompMt<<<dim3(9, 20, 20), 256, 0, stream>>>(E1, E2, Mpt);
    k_bucket<<<1, 256, 0, stream>>>(dea, eord, tm, ntl);

    k_init_h<<<(NN * 160 + 255) / 256, 256, 0, stream>>>(x, ae1, ae2, (uint32_t*)h);
    k_count<<<(EE + 255) / 256, 256, 0, stream>>>(ei, ea, deg, cnt1, cnt2);

    int nb = (NN + 255) / 256;
    k_scan1<<<nb, 256, 0, stream>>>(deg, incl, bsum, NN);
    k_scan2<<<1, 1024, 0, stream>>>(bsum, boff, nb);
    k_scan3<<<nb, 256, 0, stream>>>(deg, incl, boff, rowptr, cursor, NN);
    k_scatter<<<(EE + 255) / 256, 256, 0, stream>>>(ei, cursor, col);

    k_fragcnt<<<nb, 256, 0, stream>>>(fb, fcnt);
    int nbf = (FF + 255) / 256;
    k_scan1<<<nbf, 256, 0, stream>>>(fcnt, incl, bsum, FF);
    k_scan2<<<1, 1024, 0, stream>>>(bsum, boff, nbf);
    k_scan3<<<nbf, 256, 0, stream>>>(fcnt, incl, boff, fstart, (int*)nullptr, FF);

    for (int l = 0; l < NL; l++) {
        const float* ge1l = ge1 + (size_t)l * 6 * EMB;
        const float* ge2l = ge2 + (size_t)l * 3 * EMB;
        k_aggr<<<2048, 256, 0, stream>>>(h, ag, rowptr, col, cnt1, cnt2, ge1l, ge2l,
                                         (l == 0) ? nullptr : scv, (l == 0) ? 0 : 1);
        hipMemsetAsync(colsum, 0, 384 * 4, stream);
        hipMemsetAsync(colsq, 0, 384 * 4, stream);
        for (int c0 = 0; c0 < NN; c0 += TCH) {
            int Mc = (NN - c0 < TCH) ? (NN - c0) : TCH;
            int mt1 = (Mc + 127) / 128;
            k_mfma<1><<<dim3(5, mt1), 256, 0, stream>>>(
                ag + (size_t)c0 * 320, W1p + (size_t)l * 640 * 320, b1p + l * 640,
                t, Mc, nullptr, nullptr);
            int mt2 = (Mc + 63) / 64;
            k_mfma<2><<<dim3(3, mt2), 256, 0, stream>>>(
                t, W2p + (size_t)l * 384 * 640, b2p + l * 384,
                h + (size_t)c0 * 320, Mc, colsum, colsq);
        }
        k_bnfinal<<<1, 320, 0, stream>>>(colsum, colsq, bng + (size_t)l * EMB, bnb + (size_t)l * EMB, scv);
    }

    k_fragmean<<<(FF + 3) / 4, 256, 0, stream>>>(h, fstart, scv, fragmean);
    k_build_out<<<(ND * 640 + 255) / 256, 256, 0, stream>>>(h, fragmean, didx, fb, scv, outb16);
    k_vgather<<<(768 * 80 + 255) / 256, 256, 0, stream>>>(outb16, eord, dei, Vg);
    k_out0m<<<48, 256, 0, stream>>>(Vg, Mpt, tm, ntl, eord, o0);
    k_logits<<<DD, 128, 0, stream>>>(o0, outb16, dei, dout);
}